// Round 3
// baseline (150.496 us; speedup 1.0000x reference)
//
#include <hip/hip_runtime.h>

#define BATCH 64
#define MGT 300
#define NCLS 20
#define IMG 480.0f

#define N0 (BATCH * 3 * 60 * 60)   // 691200 cells
#define N1 (BATCH * 3 * 30 * 30)   // 172800
#define N2 (BATCH * 3 * 15 * 15)   //  43200
#define NTOT (N0 + N1 + N2)        // 907200

#define F1 (N0 * 25 / 4)           // 4,320,000 float4s in p1
#define F2 (N1 * 25 / 4)           // 1,080,000
#define F3 (N2 * 25 / 4)           //   270,000
#define FT (F1 + F2 + F3)          // 5,670,000

#define STREAM_BLOCKS 1024
#define WIN_BLOCKS 1024
#define NPART (STREAM_BLOCKS + WIN_BLOCKS)

// Anchors: s0 (10,13),(16,30),(33,23); s1 (30,61),(62,45),(59,119); s2 (116,90),(156,198),(373,326)
__constant__ float c_aw[3][3] = {{10.f, 16.f, 33.f}, {30.f, 62.f, 59.f}, {116.f, 156.f, 373.f}};
__constant__ float c_ah[3][3] = {{13.f, 30.f, 23.f}, {61.f, 45.f, 119.f}, {90.f, 198.f, 326.f}};

__device__ __forceinline__ float wave_red(float v) {
    #pragma unroll
    for (int o = 32; o > 0; o >>= 1) v += __shfl_down(v, o, 64);
    return v;
}

// Block reduction of 4 components -> 4 distinct partial slots (no atomics).
__device__ __forceinline__ void block_write4(float c0, float c1, float c2, float c3,
                                             float* __restrict__ partials, int row) {
    __shared__ float sm[4][4];
    int lane = threadIdx.x & 63;
    int wid = threadIdx.x >> 6;
    c0 = wave_red(c0); c1 = wave_red(c1); c2 = wave_red(c2); c3 = wave_red(c3);
    if (lane == 0) { sm[wid][0] = c0; sm[wid][1] = c1; sm[wid][2] = c2; sm[wid][3] = c3; }
    __syncthreads();
    if (threadIdx.x < 4) {
        float a = sm[0][threadIdx.x] + sm[1][threadIdx.x] + sm[2][threadIdx.x] + sm[3][threadIdx.x];
        partials[(size_t)row * 4 + threadIdx.x] = a;
    }
}

// One thread per (b,m) GT: best anchor per scale; atomicMax(m) = last-write-wins scatter.
__global__ void assign_kernel(const float* __restrict__ gt,
                              int* __restrict__ win0, int* __restrict__ win1, int* __restrict__ win2) {
    int t = blockIdx.x * blockDim.x + threadIdx.x;
    if (t >= BATCH * MGT) return;
    int b = t / MGT;
    int m = t - b * MGT;
    const float* g = gt + (size_t)t * 25;
    if (!(g[4] > 0.5f)) return;
    float mx = g[0], my = g[1];
    float w = g[2] * IMG, h = g[3] * IMG;
    float wh = w * h;

    const int Gs[3] = {60, 30, 15};
    int* wins[3] = {win0, win1, win2};
    #pragma unroll
    for (int s = 0; s < 3; ++s) {
        int G = Gs[s];
        int gx = min(max((int)floorf(mx * (float)G), 0), G - 1);
        int gy = min(max((int)floorf(my * (float)G), 0), G - 1);
        float bestR = -1.0f;
        int best = 0;
        #pragma unroll
        for (int a = 0; a < 3; ++a) {
            float aw = c_aw[s][a], ah = c_ah[s][a];
            float inter = fminf(w, aw) * fminf(h, ah);
            float uni = wh + aw * ah - inter;
            float r = inter / (uni + 1e-16f);
            if (r > bestR) { bestR = r; best = a; }  // strict > : argmax first-wins
        }
        int cell = ((b * 3 + best) * G + gy) * G + gx;
        atomicMax(&wins[s][cell], m);
    }
}

// Pure coalesced stream over ALL pred floats (93 MB) as float4; extract the
// conf element ((idx mod 25)==4) in-register and accumulate bce(conf,0) for
// EVERY cell. No win[] dependency (R2 lesson: stride-100B gather ran at
// ~2 TB/s effective; streaming everything runs at HBM peak).
__global__ __launch_bounds__(256) void noobj_stream_kernel(
        const float4* __restrict__ p1, const float4* __restrict__ p2, const float4* __restrict__ p3,
        float* __restrict__ partials) {
    float acc = 0.f;
    for (int i = blockIdx.x * blockDim.x + threadIdx.x; i < FT; i += gridDim.x * blockDim.x) {
        const float4* base; int li;
        if (i < F1)           { base = p1; li = i; }
        else if (i < F1 + F2) { base = p2; li = i - F1; }
        else                  { base = p3; li = i - F1 - F2; }
        float4 v = base[li];
        unsigned f = 4u * (unsigned)li;
        unsigned r = f % 25u;                 // magic-mul, compile-time constant divisor
        unsigned j0 = (29u - r) % 25u;        // (4 - r) mod 25
        if (j0 < 4u) {                        // this float4 contains one conf value
            float p = (j0 == 0) ? v.x : (j0 == 1) ? v.y : (j0 == 2) ? v.z : v.w;
            float lq = (p < 1.0f) ? fmaxf(logf(1.0f - p), -100.0f) : -100.0f;
            acc -= lq;                        // bce(p, 0)
        }
    }
    acc *= 0.5f;                              // LAMBDA_NOOBJ
    block_write4(0.f, 0.f, acc, 0.f, partials, blockIdx.x);
}

// Winner cells only (~1-3%): full coord/obj/cls terms, plus SUBTRACT the
// noObj term the stream pass added for these cells (there noObj mask = 0).
__global__ __launch_bounds__(256) void winner_kernel(
        const float* __restrict__ p1, const float* __restrict__ p2, const float* __restrict__ p3,
        const float* __restrict__ gt,
        const int* __restrict__ win0, const int* __restrict__ win1, const int* __restrict__ win2,
        float* __restrict__ partials) {
    float coord = 0.f, objL = 0.f, noObjC = 0.f, clsL = 0.f;
    for (int c = blockIdx.x * blockDim.x + threadIdx.x; c < NTOT; c += gridDim.x * blockDim.x) {
        const float* pred; const int* win; int G, s, local;
        if (c < N0)           { pred = p1; win = win0; G = 60; s = 0; local = c; }
        else if (c < N0 + N1) { pred = p2; win = win1; G = 30; s = 1; local = c - N0; }
        else                  { pred = p3; win = win2; G = 15; s = 2; local = c - N0 - N1; }
        int m = win[local];
        if (m < 0) continue;

        const float* p = pred + (size_t)local * 25;
        float pconf = p[4];
        // correction: stream added -lq for this cell; true noObj term is 0
        float lq = (pconf < 1.0f) ? fmaxf(logf(1.0f - pconf), -100.0f) : -100.0f;
        noObjC += lq;

        int gx = local % G;
        int t1 = local / G;
        int gy = t1 % G;
        int t2 = t1 / G;
        int a = t2 % 3;
        int b = t2 / 3;
        const float* g = gt + ((size_t)b * MGT + m) * 25;
        float w = g[2] * IMG, h = g[3] * IMG;
        float tx = g[0] * (float)G - (float)gx;
        float ty = g[1] * (float)G - (float)gy;
        float tw = logf(w / c_aw[s][a] + 1e-16f);
        float th = logf(h / c_ah[s][a] + 1e-16f);
        float dx = p[0] - tx, dy = p[1] - ty, dw = p[2] - tw, dh = p[3] - th;
        coord += dx * dx + dy * dy + dw * dw + dh * dh;
        float lp = (pconf > 0.0f) ? fmaxf(logf(pconf), -100.0f) : -100.0f;
        objL -= lp;
        #pragma unroll
        for (int k = 0; k < NCLS; ++k) {
            float pc = p[5 + k], tc = g[5 + k];
            float lpk = (pc > 0.0f) ? fmaxf(logf(pc), -100.0f) : -100.0f;
            float lqk = (pc < 1.0f) ? fmaxf(logf(1.0f - pc), -100.0f) : -100.0f;
            clsL -= tc * lpk + (1.0f - tc) * lqk;
        }
    }
    coord *= 5.0f;    // LAMBDA_COORD
    noObjC *= 0.5f;   // LAMBDA_NOOBJ (negative correction)
    block_write4(coord, objL, noObjC, clsL, partials, STREAM_BLOCKS + blockIdx.x);
}

// Single block: reduce NPART x 4 partials into the 5 outputs.
__global__ __launch_bounds__(256) void finalize_kernel(const float* __restrict__ partials,
                                                       float* __restrict__ out) {
    int lane = threadIdx.x & 63;
    int w = threadIdx.x >> 6;  // wave w reduces component w
    float s = 0.f;
    for (int i = lane; i < NPART; i += 64) s += partials[i * 4 + w];
    s = wave_red(s);
    __shared__ float sm[4];
    if (lane == 0) sm[w] = s;
    __syncthreads();
    if (threadIdx.x == 0) {
        out[0] = sm[0] + sm[1] + sm[2] + sm[3];
        out[1] = sm[0];  // coord
        out[2] = sm[1];  // objL
        out[3] = sm[2];  // noObjL
        out[4] = sm[3];  // clsL
    }
}

extern "C" void kernel_launch(void* const* d_in, const int* in_sizes, int n_in,
                              void* d_out, int out_size, void* d_ws, size_t ws_size,
                              hipStream_t stream) {
    const float* p1 = (const float*)d_in[0];  // (64,3,60,60,25)
    const float* p2 = (const float*)d_in[1];  // (64,3,30,30,25)
    const float* p3 = (const float*)d_in[2];  // (64,3,15,15,25)
    const float* gt = (const float*)d_in[3];  // (64,300,25)
    float* out = (float*)d_out;               // [total, coord, objL, noObjL, clsL]

    int* win0 = (int*)d_ws;
    int* win1 = win0 + N0;
    int* win2 = win1 + N1;
    float* partials = (float*)(win2 + N2);    // NPART*4 floats
    size_t winBytes = (size_t)NTOT * sizeof(int);

    hipMemsetAsync(d_ws, 0xFF, winBytes, stream);  // winners = -1

    int nGT = BATCH * MGT;
    assign_kernel<<<(nGT + 255) / 256, 256, 0, stream>>>(gt, win0, win1, win2);

    noobj_stream_kernel<<<STREAM_BLOCKS, 256, 0, stream>>>(
        (const float4*)p1, (const float4*)p2, (const float4*)p3, partials);
    winner_kernel<<<WIN_BLOCKS, 256, 0, stream>>>(p1, p2, p3, gt, win0, win1, win2, partials);
    finalize_kernel<<<1, 256, 0, stream>>>(partials, out);
}